// Round 8
// baseline (61.978 us; speedup 1.0000x reference)
//
#include <hip/hip_runtime.h>

#define GROUPS 64
#define DIMS 8
#define ACCW 10      // 8 sums + ssq + count
#define LSTRIDE 11   // LDS int stride (break pow2 bank pattern)
#define BPI 128      // blocks per image
#define BLK 256
#define NIMG 8
#define SCALE 262144.0f          // 2^18
#define INV_SCALE (1.0f / 262144.0f)

__global__ void k_zero(unsigned long long* p, int n) {
    int i = blockIdx.x * blockDim.x + threadIdx.x;
    if (i < n) p[i] = 0ull;
}

// DIAGNOSTIC: identical grid + index pattern + loads as k_accum, but no
// LDS/atomics. asm-volatile keep-alive prevents DCE of the load chain.
// Its rocprof dur_us is the pure-streaming floor of this access pattern.
__global__ __launch_bounds__(BLK) void k_load(const float* __restrict__ pred,
                                              const int* __restrict__ gt,
                                              int N) {
    const int tid = threadIdx.x;
    const int b = blockIdx.y;
    const float4* pb = (const float4*)(pred + (size_t)b * N * DIMS);
    const int* gb = gt + (size_t)b * N;
    float s = 0.f;
    int gs = 0;
    for (int idx = blockIdx.x * BLK + tid; idx < N; idx += BPI * BLK) {
        int g = gb[idx];
        float4 p0 = pb[2 * idx];
        float4 p1 = pb[2 * idx + 1];
        gs += g;
        s += p0.x + p0.y + p0.z + p0.w + p1.x + p1.y + p1.z + p1.w;
    }
    asm volatile("" :: "v"(s), "v"(gs));
}

__global__ __launch_bounds__(BLK) void k_accum(const float* __restrict__ pred,
                                               const int* __restrict__ gt,
                                               unsigned long long* __restrict__ gacc,
                                               int N) {
    __shared__ int acc[4][GROUPS * LSTRIDE];
    const int tid = threadIdx.x;
    const int wave = tid >> 6;
    const int b = blockIdx.y;
    for (int i = tid; i < 4 * GROUPS * LSTRIDE; i += BLK) ((int*)acc)[i] = 0;
    __syncthreads();

    const float4* pb = (const float4*)(pred + (size_t)b * N * DIMS);
    const int* gb = gt + (size_t)b * N;
    for (int idx = blockIdx.x * BLK + tid; idx < N; idx += BPI * BLK) {
        int g = gb[idx];
        float4 p0 = pb[2 * idx];
        float4 p1 = pb[2 * idx + 1];
        int* a = &acc[wave][g * LSTRIDE];
        atomicAdd(a + 0, __float2int_rn(p0.x * SCALE));
        atomicAdd(a + 1, __float2int_rn(p0.y * SCALE));
        atomicAdd(a + 2, __float2int_rn(p0.z * SCALE));
        atomicAdd(a + 3, __float2int_rn(p0.w * SCALE));
        atomicAdd(a + 4, __float2int_rn(p1.x * SCALE));
        atomicAdd(a + 5, __float2int_rn(p1.y * SCALE));
        atomicAdd(a + 6, __float2int_rn(p1.z * SCALE));
        atomicAdd(a + 7, __float2int_rn(p1.w * SCALE));
        float ssq = p0.x*p0.x + p0.y*p0.y + p0.z*p0.z + p0.w*p0.w
                  + p1.x*p1.x + p1.y*p1.y + p1.z*p1.z + p1.w*p1.w;
        atomicAdd(a + 8, __float2int_rn(ssq * SCALE));
        atomicAdd(a + 9, 1);
    }
    __syncthreads();

    for (int i = tid; i < GROUPS * ACCW; i += BLK) {
        int g = i / ACCW, k = i % ACCW;
        long long v = (long long)acc[0][g * LSTRIDE + k]
                    + (long long)acc[1][g * LSTRIDE + k]
                    + (long long)acc[2][g * LSTRIDE + k]
                    + (long long)acc[3][g * LSTRIDE + k];
        atomicAdd(&gacc[(b * GROUPS + g) * ACCW + k], (unsigned long long)v);
    }
}

__global__ __launch_bounds__(512) void k_final(const unsigned long long* __restrict__ gacc,
                                               float* __restrict__ out) {
    __shared__ float sm[NIMG][GROUPS][DIMS + 1];
    __shared__ float lossArr[NIMG];
    const int tid = threadIdx.x;
    const int b = tid >> 6;     // image (wave)
    const int g = tid & 63;     // group (lane)

    const unsigned long long* ga = gacc + (b * GROUPS + g) * ACCW;
    float c = (float)(long long)ga[9];
    float ssq = (float)(long long)ga[8] * INV_SCALE;
    float safe = fmaxf(c, 1.f);
    float m[DIMS];
    float msq = 0.f;
    for (int d = 0; d < DIMS; ++d) {
        m[d] = ((float)(long long)ga[d] * INV_SCALE) / safe;
        sm[b][g][d] = m[d];
        msq += m[d] * m[d];
    }
    bool present = c > 0.f;
    sm[b][g][DIMS] = present ? 1.f : 0.f;

    float sumsq = ssq - c * msq;
    float pull_g = present ? sumsq / (safe * (float)DIMS) : 0.f;

    unsigned long long mask = __ballot(present);
    float num = (float)__popcll(mask);

    float pull = pull_g;
    for (int off = 32; off; off >>= 1) pull += __shfl_xor(pull, off);

    __syncthreads();

    float pg = 0.f;
    if (present) {
        for (int j = 0; j < GROUPS; ++j) {
            float pm = sm[b][j][DIMS];
            float d2 = 0.f;
            for (int d = 0; d < DIMS; ++d) {
                float t = m[d] - sm[b][j][d];
                d2 += t * t;
            }
            pg += pm * expf(-d2);
        }
    }
    for (int off = 32; off; off >>= 1) pg += __shfl_xor(pg, off);

    if (g == 0) {
        float push = (pg - num) / ((num - 1.f) * num + 1e-6f) * 0.5f;
        float pl = pull / (num + 1e-6f);
        lossArr[b] = push + pl;
    }
    __syncthreads();

    if (tid == 0) {
        float s = 0.f;
        for (int i = 0; i < NIMG; ++i) s += lossArr[i];
        out[0] = s * (1.f / (float)NIMG);
    }
}

extern "C" void kernel_launch(void* const* d_in, const int* in_sizes, int n_in,
                              void* d_out, int out_size, void* d_ws, size_t ws_size,
                              hipStream_t stream) {
    const float* pred = (const float*)d_in[0];
    const int* gt = (const int*)d_in[1];
    const int N = in_sizes[1] / NIMG;   // 500000

    unsigned long long* gacc = (unsigned long long*)d_ws;  // [NIMG][GROUPS][ACCW]
    const int accN = NIMG * GROUPS * ACCW;

    dim3 grid(BPI, NIMG);
    // diagnostic pure-load pass (no side effects; rocprof-only payload)
    k_load<<<grid, BLK, 0, stream>>>(pred, gt, N);

    k_zero<<<(accN + 255) / 256, 256, 0, stream>>>(gacc, accN);
    k_accum<<<grid, BLK, 0, stream>>>(pred, gt, gacc, N);
    k_final<<<1, 512, 0, stream>>>(gacc, (float*)d_out);
}